// Round 2
// baseline (42693.155 us; speedup 1.0000x reference)
//
#include <hip/hip_runtime.h>
#include <hip/hip_bf16.h>
#include <hip/hip_cooperative_groups.h>
#include <math.h>

namespace cg = cooperative_groups;

#define BB 256
#define SS 256
#define DIN 300
#define D2 300
#define HH 512

__device__ __forceinline__ float sigf(float x) { return 1.0f / (1.0f + expf(-x)); }

// ---------------------------------------------------------------------------
// xp = tanh(x @ W_in + b_in), written TRANSPOSED to [S][B][D2] so the scan's
// phase-A epilogue reads a contiguous 256x300 slice per step.
// Tile 32x64, double-buffered LDS. M=65536 rows of x ([B][S] flattened).
// ---------------------------------------------------------------------------
__global__ __launch_bounds__(256) void xp_kernel(
    const float* __restrict__ A,      // x  [65536 x 300]
    const float* __restrict__ Bm,     // W_in [300 x 300]
    const float* __restrict__ bias,   // b_in [300]
    float* __restrict__ C)            // xp [S][B][300]
{
    __shared__ float As[2][16][34];
    __shared__ float Bs[2][16][64];
    const int tid = threadIdx.x;
    const int m0 = blockIdx.y * 32;
    const int n0 = blockIdx.x * 64;
    const int tx = tid & 15;
    const int ty = tid >> 4;
    float acc[2][4] = {{0.f,0.f,0.f,0.f},{0.f,0.f,0.f,0.f}};
    const int NC = (DIN + 15) >> 4;   // 19

    float ra0, ra1, rb[4];
    auto load_regs = [&](int c) {
        const int k0 = c << 4;
        int e = tid, kk = e & 15, r = e >> 4;
        ra0 = (k0 + kk < DIN) ? A[(size_t)(m0 + r) * DIN + k0 + kk] : 0.f;
        e = tid + 256; kk = e & 15; r = e >> 4;
        ra1 = (k0 + kk < DIN) ? A[(size_t)(m0 + r) * DIN + k0 + kk] : 0.f;
#pragma unroll
        for (int i = 0; i < 4; ++i) {
            int e2 = tid + (i << 8);
            int kk2 = e2 >> 6, cc = e2 & 63;
            rb[i] = (k0 + kk2 < DIN && n0 + cc < D2) ? Bm[(k0 + kk2) * D2 + n0 + cc] : 0.f;
        }
    };
    auto store_lds = [&](int buf) {
        int e = tid; As[buf][e & 15][e >> 4] = ra0;
        e = tid + 256; As[buf][e & 15][e >> 4] = ra1;
#pragma unroll
        for (int i = 0; i < 4; ++i) {
            int e2 = tid + (i << 8);
            Bs[buf][e2 >> 6][e2 & 63] = rb[i];
        }
    };

    load_regs(0); store_lds(0);
    for (int c = 0; c < NC; ++c) {
        __syncthreads();
        if (c + 1 < NC) load_regs(c + 1);
        const int buf = c & 1;
#pragma unroll
        for (int kk = 0; kk < 16; ++kk) {
            float2 a = *(const float2*)&As[buf][kk][ty * 2];
            float4 b = *(const float4*)&Bs[buf][kk][tx * 4];
            acc[0][0] += a.x * b.x; acc[0][1] += a.x * b.y;
            acc[0][2] += a.x * b.z; acc[0][3] += a.x * b.w;
            acc[1][0] += a.y * b.x; acc[1][1] += a.y * b.y;
            acc[1][2] += a.y * b.z; acc[1][3] += a.y * b.w;
        }
        if (c + 1 < NC) store_lds((c + 1) & 1);
    }

#pragma unroll
    for (int j = 0; j < 2; ++j) {
        const int r = m0 + ty * 2 + j;
        const int b = r >> 8;           // SS = 256
        const int s = r & 255;
#pragma unroll
        for (int i = 0; i < 4; ++i) {
            const int col = n0 + tx * 4 + i;
            if (col < D2) {
                C[((size_t)s * BB + b) * D2 + col] = tanhf(acc[j][i] + bias[col]);
            }
        }
    }
}

// ---------------------------------------------------------------------------
// Phase A/B tile: 16(M) x 64(N), K-blocked 16, double-buffered.
// out = 2*sigmoid(A@Bm) * aux   (elementwise over the tile)
// ---------------------------------------------------------------------------
__device__ __forceinline__ void mog_tile(
    const float* __restrict__ A, int lda, int K,
    const float* __restrict__ Bm, int N,          // ldb == N
    float* __restrict__ C, int ldc,
    const float* __restrict__ aux, int auxld,
    int m0, int n0, float* smem, int tid)
{
    float (*As)[16][18] = (float(*)[16][18])smem;              // 2*16*18
    float (*Bs)[16][64] = (float(*)[16][64])(smem + 2 * 16 * 18);
    const int tx = tid & 15;
    const int ty = tid >> 4;
    float acc[4] = {0.f, 0.f, 0.f, 0.f};
    const int NC = (K + 15) >> 4;

    float ra, rb[4];
    auto load_regs = [&](int c) {
        const int k0 = c << 4;
        int kk = tid & 15, r = tid >> 4;
        ra = (k0 + kk < K) ? A[(m0 + r) * lda + k0 + kk] : 0.f;
#pragma unroll
        for (int i = 0; i < 4; ++i) {
            int e2 = tid + (i << 8);
            int kk2 = e2 >> 6, cc = e2 & 63;
            rb[i] = (k0 + kk2 < K && n0 + cc < N) ? Bm[(k0 + kk2) * N + n0 + cc] : 0.f;
        }
    };
    auto store_lds = [&](int buf) {
        As[buf][tid & 15][tid >> 4] = ra;
#pragma unroll
        for (int i = 0; i < 4; ++i) {
            int e2 = tid + (i << 8);
            Bs[buf][e2 >> 6][e2 & 63] = rb[i];
        }
    };

    load_regs(0); store_lds(0);
    for (int c = 0; c < NC; ++c) {
        __syncthreads();
        if (c + 1 < NC) load_regs(c + 1);
        const int buf = c & 1;
#pragma unroll
        for (int kk = 0; kk < 16; ++kk) {
            float a = As[buf][kk][ty];
            float4 b = *(const float4*)&Bs[buf][kk][tx * 4];
            acc[0] += a * b.x; acc[1] += a * b.y;
            acc[2] += a * b.z; acc[3] += a * b.w;
        }
        if (c + 1 < NC) store_lds((c + 1) & 1);
    }

    const int r = m0 + ty;
#pragma unroll
    for (int i = 0; i < 4; ++i) {
        const int col = n0 + tx * 4 + i;
        if (col < N) {
            C[(size_t)r * ldc + col] = 2.0f * sigf(acc[i]) * aux[(size_t)r * auxld + col];
        }
    }
}

// ---------------------------------------------------------------------------
// Phase C tile: gates GEMM (K = 300 over xt2@Wih then 512 over ht2@Whh) +
// LSTM cell update. Tile 16 rows x 32 h x 4 gate segs.
// ---------------------------------------------------------------------------
__device__ __forceinline__ void gates_tile(
    const float* __restrict__ xt2, const float* __restrict__ ht2,
    const float* __restrict__ Wih, const float* __restrict__ Whh,
    const float* __restrict__ bih, const float* __restrict__ bhh,
    float* __restrict__ ct, float* __restrict__ ht,
    __hip_bfloat16* __restrict__ hseq, int t,
    int h0, int b0, float* smem, int tid)
{
    float (*As)[16][18]  = (float(*)[16][18])smem;
    float (*Bs)[16][128] = (float(*)[16][128])(smem + 2 * 16 * 18);
    const int hx = tid & 31;
    const int rp = tid >> 5;
    float acc[2][4] = {{0.f,0.f,0.f,0.f},{0.f,0.f,0.f,0.f}};

    const int NC1 = (D2 + 15) >> 4;   // 19
    const int NC2 = HH >> 4;          // 32
    const int NC = NC1 + NC2;         // 51

    float ra, rb[8];
    auto load_regs = [&](int c) {
        const float* Ap; const float* W; int lda, K, k0;
        if (c < NC1) { Ap = xt2; W = Wih; lda = D2; K = D2; k0 = c << 4; }
        else         { Ap = ht2; W = Whh; lda = HH; K = HH; k0 = (c - NC1) << 4; }
        int kk = tid & 15, r = tid >> 4;
        ra = (k0 + kk < K) ? Ap[(b0 + r) * lda + k0 + kk] : 0.f;
#pragma unroll
        for (int i = 0; i < 8; ++i) {
            int e2 = tid + (i << 8);
            int kk2 = e2 >> 7, cc = e2 & 127, s = cc >> 5, hh = cc & 31;
            rb[i] = (k0 + kk2 < K) ? W[(size_t)(k0 + kk2) * 2048 + s * 512 + h0 + hh] : 0.f;
        }
    };
    auto store_lds = [&](int buf) {
        As[buf][tid & 15][tid >> 4] = ra;
#pragma unroll
        for (int i = 0; i < 8; ++i) {
            int e2 = tid + (i << 8);
            int kk2 = e2 >> 7, cc = e2 & 127, s = cc >> 5, hh = cc & 31;
            Bs[buf][kk2][hh * 4 + s] = rb[i];
        }
    };

    load_regs(0); store_lds(0);
    for (int c = 0; c < NC; ++c) {
        __syncthreads();
        if (c + 1 < NC) load_regs(c + 1);
        const int buf = c & 1;
#pragma unroll
        for (int kk = 0; kk < 16; ++kk) {
            float2 a = *(const float2*)&As[buf][kk][rp * 2];
            float4 b = *(const float4*)&Bs[buf][kk][hx * 4];
            acc[0][0] += a.x * b.x; acc[0][1] += a.x * b.y;
            acc[0][2] += a.x * b.z; acc[0][3] += a.x * b.w;
            acc[1][0] += a.y * b.x; acc[1][1] += a.y * b.y;
            acc[1][2] += a.y * b.z; acc[1][3] += a.y * b.w;
        }
        if (c + 1 < NC) store_lds((c + 1) & 1);
    }

    const int h = h0 + hx;
    const float bi0 = bih[h] + bhh[h];
    const float bi1 = bih[512 + h] + bhh[512 + h];
    const float bi2 = bih[1024 + h] + bhh[1024 + h];
    const float bi3 = bih[1536 + h] + bhh[1536 + h];
#pragma unroll
    for (int j = 0; j < 2; ++j) {
        const int r = b0 + rp * 2 + j;
        const float ig = acc[j][0] + bi0;
        const float fg = acc[j][1] + bi1;
        const float gg = acc[j][2] + bi2;
        const float og = acc[j][3] + bi3;
        const size_t idx = (size_t)r * 512 + h;
        const float c_old = ct[idx];
        const float cn = sigf(fg) * c_old + sigf(ig) * tanhf(gg);
        const float hn = sigf(og) * tanhf(cn);
        ct[idx] = cn;
        ht[idx] = hn;
        hseq[((size_t)r * SS + t) * 512 + h] = __float2bfloat16(hn);
    }
}

// ---------------------------------------------------------------------------
// Persistent cooperative scan: 256 WGs x 256 threads, 3 grid syncs per step.
// ---------------------------------------------------------------------------
__global__ __launch_bounds__(256, 1) void scan_kernel(
    const float* __restrict__ xp,   // [S][B][D2]
    const float* __restrict__ Q, const float* __restrict__ R,
    const float* __restrict__ Wih, const float* __restrict__ Whh,
    const float* __restrict__ bih, const float* __restrict__ bhh,
    float* __restrict__ xt2, float* __restrict__ ht, float* __restrict__ ht2,
    float* __restrict__ ct, __hip_bfloat16* __restrict__ hseq)
{
    cg::grid_group grid = cg::this_grid();
    __shared__ float smem[2 * 16 * 18 + 2 * 16 * 128];   // 18.7 KB (phase C max)
    const int w = blockIdx.x;
    const int tid = threadIdx.x;

    // zero-init ht, ct (ws is poisoned before every launch)
    for (size_t i = (size_t)w * 256 + tid; i < (size_t)BB * HH; i += 256 * 256) {
        ht[i] = 0.f;
        ct[i] = 0.f;
    }
    grid.sync();

    for (int t = 0; t < SS; ++t) {
        // Phase A: xt2 = 2*sig(ht@Q) * xp_t   M=256 K=512 N=300; 16x5=80 tiles
        if (w < 80) {
            const int m0 = (w / 5) * 16;
            const int n0 = (w % 5) * 64;
            mog_tile(ht, HH, HH, Q, D2, xt2, D2,
                     xp + (size_t)t * BB * D2, D2, m0, n0, smem, tid);
        }
        grid.sync();

        // Phase B: ht2 = 2*sig(xt2@R) * ht    M=256 K=300 N=512; 16x8=128 tiles
        if (w < 128) {
            const int m0 = (w >> 3) * 16;
            const int n0 = (w & 7) * 64;
            mog_tile(xt2, D2, D2, R, HH, ht2, HH, ht, HH, m0, n0, smem, tid);
        }
        grid.sync();

        // Phase C: gates + cell update; 16x16 = 256 tiles
        {
            const int h0 = (w & 15) * 32;
            const int b0 = (w >> 4) * 16;
            gates_tile(xt2, ht2, Wih, Whh, bih, bhh, ct, ht, hseq, t,
                       h0, b0, smem, tid);
        }
        grid.sync();
    }
}

// ---------------------------------------------------------------------------
// Conv + relu + maxpool over time. One WG per batch row. hseq is bf16.
// ---------------------------------------------------------------------------
__global__ __launch_bounds__(256) void conv_kernel(
    const __hip_bfloat16* __restrict__ hseq,
    const float* __restrict__ w3, const float* __restrict__ cb3,
    const float* __restrict__ w4, const float* __restrict__ cb4,
    const float* __restrict__ w5, const float* __restrict__ cb5,
    float* __restrict__ feats)
{
    __shared__ float sh[20 * 516];
    __shared__ float part[16 * 16 * 9];
    __shared__ int rmax[9];
    const int b = blockIdx.x;
    const int tid = threadIdx.x;
    if (tid < 9) rmax[tid] = 0;
    const int wv = tid >> 6, lane = tid & 63;
    const int t0l = lane >> 2, hs = lane & 3;

    for (int p = 0; p < 16; ++p) {
        __syncthreads();
#pragma unroll
        for (int i = 0; i < 5; ++i) {
            int e = tid + (i << 8);
            int row = e >> 6, q = e & 63;
            int tg = p * 16 + row;
            float v[8];
            if (tg < SS) {
                uint4 u = *(const uint4*)(hseq + (((size_t)b * SS + tg) << 9) + (q << 3));
                v[0] = __uint_as_float(u.x << 16); v[1] = __uint_as_float(u.x & 0xffff0000u);
                v[2] = __uint_as_float(u.y << 16); v[3] = __uint_as_float(u.y & 0xffff0000u);
                v[4] = __uint_as_float(u.z << 16); v[5] = __uint_as_float(u.z & 0xffff0000u);
                v[6] = __uint_as_float(u.w << 16); v[7] = __uint_as_float(u.w & 0xffff0000u);
            } else {
#pragma unroll
                for (int j = 0; j < 8; ++j) v[j] = 0.f;
            }
#pragma unroll
            for (int j = 0; j < 8; ++j) sh[row * 516 + q * 8 + j] = v[j];
        }
        __syncthreads();

        float acc[9];
#pragma unroll
        for (int j = 0; j < 9; ++j) acc[j] = 0.f;
        for (int k = 0; k < 32; ++k) {
            const int h = (wv << 7) + (k << 2) + hs;
            const float v0 = sh[(t0l + 0) * 516 + h];
            const float v1 = sh[(t0l + 1) * 516 + h];
            const float v2 = sh[(t0l + 2) * 516 + h];
            const float v3 = sh[(t0l + 3) * 516 + h];
            const float v4 = sh[(t0l + 4) * 516 + h];
#pragma unroll
            for (int f = 0; f < 3; ++f) {
                acc[f]     += v0 * w3[(f * 3 + 0) * 512 + h] + v1 * w3[(f * 3 + 1) * 512 + h]
                            + v2 * w3[(f * 3 + 2) * 512 + h];
                acc[3 + f] += v0 * w4[(f * 4 + 0) * 512 + h] + v1 * w4[(f * 4 + 1) * 512 + h]
                            + v2 * w4[(f * 4 + 2) * 512 + h] + v3 * w4[(f * 4 + 3) * 512 + h];
                acc[6 + f] += v0 * w5[(f * 5 + 0) * 512 + h] + v1 * w5[(f * 5 + 1) * 512 + h]
                            + v2 * w5[(f * 5 + 2) * 512 + h] + v3 * w5[(f * 5 + 3) * 512 + h]
                            + v4 * w5[(f * 5 + 4) * 512 + h];
            }
        }
        const int pi = (wv << 2) + hs;
#pragma unroll
        for (int j = 0; j < 9; ++j) part[(pi * 16 + t0l) * 9 + j] = acc[j];
        __syncthreads();
        if (tid < 144) {
            const int tl = tid / 9, j = tid % 9;
            float s = 0.f;
#pragma unroll
            for (int pp = 0; pp < 16; ++pp) s += part[(pp * 16 + tl) * 9 + j];
            const int fsz = j < 3 ? 3 : (j < 6 ? 4 : 5);
            const int t0 = p * 16 + tl;
            if (t0 <= SS - fsz) {
                const float bias = j < 3 ? cb3[j] : (j < 6 ? cb4[j - 3] : cb5[j - 6]);
                float v = s + bias;
                v = v > 0.f ? v : 0.f;
                atomicMax(&rmax[j], __float_as_int(v));
            }
        }
    }
    __syncthreads();
    if (tid < 9) feats[b * 9 + tid] = __int_as_float(rmax[tid]);
}

__global__ void final_kernel(const float* __restrict__ feats,
                             const float* __restrict__ lin_w,
                             const float* __restrict__ lin_b,
                             float* __restrict__ out)
{
    const int b = threadIdx.x;
    float o0 = lin_b[0], o1 = lin_b[1];
#pragma unroll
    for (int j = 0; j < 9; ++j) {
        const float f = feats[b * 9 + j];
        o0 += f * lin_w[j * 2 + 0];
        o1 += f * lin_w[j * 2 + 1];
    }
    out[b * 2 + 0] = o0;
    out[b * 2 + 1] = o1;
}

extern "C" void kernel_launch(void* const* d_in, const int* in_sizes, int n_in,
                              void* d_out, int out_size, void* d_ws, size_t ws_size,
                              hipStream_t stream) {
    const float* x    = (const float*)d_in[0];
    const float* W_in = (const float*)d_in[1];
    const float* b_in = (const float*)d_in[2];
    const float* Wih  = (const float*)d_in[3];
    const float* Whh  = (const float*)d_in[4];
    const float* bih  = (const float*)d_in[5];
    const float* bhh  = (const float*)d_in[6];
    const float* Q    = (const float*)d_in[7];
    const float* R    = (const float*)d_in[8];
    const float* lin_w = (const float*)d_in[9];
    const float* lin_b = (const float*)d_in[10];
    const float* w3 = (const float*)d_in[11];
    const float* cb3 = (const float*)d_in[12];
    const float* w4 = (const float*)d_in[13];
    const float* cb4 = (const float*)d_in[14];
    const float* w5 = (const float*)d_in[15];
    const float* cb5 = (const float*)d_in[16];

    float* ws = (float*)d_ws;
    float* xp    = ws;                              // [S][B][300]
    float* xt2   = xp + (size_t)BB * SS * D2;       // 256*300
    float* ht    = xt2 + BB * D2;                   // 256*512
    float* ht2   = ht + BB * HH;                    // 256*512
    float* ct    = ht2 + BB * HH;                   // 256*512
    float* feats = ct + BB * HH;                    // 256*9
    __hip_bfloat16* hseq = (__hip_bfloat16*)(feats + BB * 9);  // [B][S][512] bf16

    // xp = tanh(x @ W_in + b_in), transposed to [S][B][D2]
    xp_kernel<<<dim3(5, 2048), 256, 0, stream>>>(x, W_in, b_in, xp);

    // persistent cooperative scan
    void* args[] = {(void*)&xp, (void*)&Q, (void*)&R, (void*)&Wih, (void*)&Whh,
                    (void*)&bih, (void*)&bhh, (void*)&xt2, (void*)&ht, (void*)&ht2,
                    (void*)&ct, (void*)&hseq};
    hipLaunchCooperativeKernel((const void*)scan_kernel, dim3(256), dim3(256),
                               args, 0, stream);

    conv_kernel<<<dim3(256), 256, 0, stream>>>(hseq, w3, cb3, w4, cb4, w5, cb5, feats);
    final_kernel<<<dim3(1), 256, 0, stream>>>(feats, lin_w, lin_b, (float*)d_out);
}

// Round 3
// 28405.432 us; speedup vs baseline: 1.5030x; 1.5030x over previous
//
#include <hip/hip_runtime.h>
#include <hip/hip_bf16.h>
#include <hip/hip_cooperative_groups.h>
#include <math.h>

namespace cg = cooperative_groups;

#define BB 256
#define SS 256
#define DIN 300
#define D2 300
#define HH 512

__device__ __forceinline__ float sigf(float x) { return 1.0f / (1.0f + expf(-x)); }

// Cross-XCD coherent accesses: sc1 (bypass non-coherent per-XCD L2, served by L3).
__device__ __forceinline__ float ld_sc(const float* p) {
    return __hip_atomic_load(p, __ATOMIC_RELAXED, __HIP_MEMORY_SCOPE_AGENT);
}
__device__ __forceinline__ void st_sc(float* p, float v) {
    __hip_atomic_store(p, v, __ATOMIC_RELAXED, __HIP_MEMORY_SCOPE_AGENT);
}

// Lightweight grid barrier: one fresh counter per event (no ABA). All data
// exchanged through sc1 accesses is visible at L3; __syncthreads drains vmcnt
// before thread0 arrives, release-add orders the arrival after the drain.
// Crucially: NO acquire/L2-invalidate anywhere -> weights stay L2-resident.
__device__ __forceinline__ void gbar(int* cnt, int tid) {
    __syncthreads();
    if (tid == 0) {
        __hip_atomic_fetch_add(cnt, 1, __ATOMIC_RELEASE, __HIP_MEMORY_SCOPE_AGENT);
        while (__hip_atomic_load(cnt, __ATOMIC_RELAXED, __HIP_MEMORY_SCOPE_AGENT) < 256) {
            __builtin_amdgcn_s_sleep(1);
        }
    }
    __syncthreads();
}

// ---------------------------------------------------------------------------
// xp = tanh(x @ W_in + b_in), transposed to [S][B][D2].
// ---------------------------------------------------------------------------
__global__ __launch_bounds__(256) void xp_kernel(
    const float* __restrict__ A, const float* __restrict__ Bm,
    const float* __restrict__ bias, float* __restrict__ C)
{
    __shared__ float As[2][16][34];
    __shared__ float Bs[2][16][64];
    const int tid = threadIdx.x;
    const int m0 = blockIdx.y * 32;
    const int n0 = blockIdx.x * 64;
    const int tx = tid & 15;
    const int ty = tid >> 4;
    float acc[2][4] = {{0.f,0.f,0.f,0.f},{0.f,0.f,0.f,0.f}};
    const int NC = (DIN + 15) >> 4;

    float ra0, ra1, rb[4];
    auto load_regs = [&](int c) {
        const int k0 = c << 4;
        int e = tid, kk = e & 15, r = e >> 4;
        ra0 = (k0 + kk < DIN) ? A[(size_t)(m0 + r) * DIN + k0 + kk] : 0.f;
        e = tid + 256; kk = e & 15; r = e >> 4;
        ra1 = (k0 + kk < DIN) ? A[(size_t)(m0 + r) * DIN + k0 + kk] : 0.f;
#pragma unroll
        for (int i = 0; i < 4; ++i) {
            int e2 = tid + (i << 8);
            int kk2 = e2 >> 6, cc = e2 & 63;
            rb[i] = (k0 + kk2 < DIN && n0 + cc < D2) ? Bm[(k0 + kk2) * D2 + n0 + cc] : 0.f;
        }
    };
    auto store_lds = [&](int buf) {
        int e = tid; As[buf][e & 15][e >> 4] = ra0;
        e = tid + 256; As[buf][e & 15][e >> 4] = ra1;
#pragma unroll
        for (int i = 0; i < 4; ++i) {
            int e2 = tid + (i << 8);
            Bs[buf][e2 >> 6][e2 & 63] = rb[i];
        }
    };

    load_regs(0); store_lds(0);
    for (int c = 0; c < NC; ++c) {
        __syncthreads();
        if (c + 1 < NC) load_regs(c + 1);
        const int buf = c & 1;
#pragma unroll
        for (int kk = 0; kk < 16; ++kk) {
            float2 a = *(const float2*)&As[buf][kk][ty * 2];
            float4 b = *(const float4*)&Bs[buf][kk][tx * 4];
            acc[0][0] += a.x * b.x; acc[0][1] += a.x * b.y;
            acc[0][2] += a.x * b.z; acc[0][3] += a.x * b.w;
            acc[1][0] += a.y * b.x; acc[1][1] += a.y * b.y;
            acc[1][2] += a.y * b.z; acc[1][3] += a.y * b.w;
        }
        if (c + 1 < NC) store_lds((c + 1) & 1);
    }

#pragma unroll
    for (int j = 0; j < 2; ++j) {
        const int r = m0 + ty * 2 + j;
        const int b = r >> 8;
        const int s = r & 255;
#pragma unroll
        for (int i = 0; i < 4; ++i) {
            const int col = n0 + tx * 4 + i;
            if (col < D2) {
                C[((size_t)s * BB + b) * D2 + col] = tanhf(acc[j][i] + bias[col]);
            }
        }
    }
}

// ---------------------------------------------------------------------------
// Phase A/B tile: 16(M) x 64(N). A-operand + (optionally) aux are cross-WG
// (sc1); weights Bm are regular loads (L2-cached). Output via sc1.
// ---------------------------------------------------------------------------
template <bool AUXSC>
__device__ __forceinline__ void mog_tile(
    const float* __restrict__ A, int lda, int K,
    const float* __restrict__ Bm, int N,
    float* __restrict__ C, int ldc,
    const float* __restrict__ aux, int auxld,
    int m0, int n0, float* smem, int tid)
{
    float (*As)[16][18] = (float(*)[16][18])smem;
    float (*Bs)[16][64] = (float(*)[16][64])(smem + 2 * 16 * 18);
    const int tx = tid & 15;
    const int ty = tid >> 4;
    float acc[4] = {0.f, 0.f, 0.f, 0.f};
    const int NC = (K + 15) >> 4;

    float ra, rb[4];
    auto load_regs = [&](int c) {
        const int k0 = c << 4;
        int kk = tid & 15, r = tid >> 4;
        ra = (k0 + kk < K) ? ld_sc(&A[(m0 + r) * lda + k0 + kk]) : 0.f;
#pragma unroll
        for (int i = 0; i < 4; ++i) {
            int e2 = tid + (i << 8);
            int kk2 = e2 >> 6, cc = e2 & 63;
            rb[i] = (k0 + kk2 < K && n0 + cc < N) ? Bm[(k0 + kk2) * N + n0 + cc] : 0.f;
        }
    };
    auto store_lds = [&](int buf) {
        As[buf][tid & 15][tid >> 4] = ra;
#pragma unroll
        for (int i = 0; i < 4; ++i) {
            int e2 = tid + (i << 8);
            Bs[buf][e2 >> 6][e2 & 63] = rb[i];
        }
    };

    load_regs(0); store_lds(0);
    for (int c = 0; c < NC; ++c) {
        __syncthreads();
        if (c + 1 < NC) load_regs(c + 1);
        const int buf = c & 1;
#pragma unroll
        for (int kk = 0; kk < 16; ++kk) {
            float a = As[buf][kk][ty];
            float4 b = *(const float4*)&Bs[buf][kk][tx * 4];
            acc[0] += a * b.x; acc[1] += a * b.y;
            acc[2] += a * b.z; acc[3] += a * b.w;
        }
        if (c + 1 < NC) store_lds((c + 1) & 1);
    }

    const int r = m0 + ty;
#pragma unroll
    for (int i = 0; i < 4; ++i) {
        const int col = n0 + tx * 4 + i;
        if (col < N) {
            float ax = AUXSC ? ld_sc(&aux[(size_t)r * auxld + col])
                             : aux[(size_t)r * auxld + col];
            st_sc(&C[(size_t)r * ldc + col], 2.0f * sigf(acc[i]) * ax);
        }
    }
}

// ---------------------------------------------------------------------------
// Phase C: gates GEMM + cell update. Bs layout [kk][seg][33]: conflict-free
// stores, broadcast-friendly reads. ct lives in the caller's registers.
// ---------------------------------------------------------------------------
__device__ __forceinline__ void gates_tile(
    const float* __restrict__ xt2, const float* __restrict__ ht2,
    const float* __restrict__ Wih, const float* __restrict__ Whh,
    const float* __restrict__ bih, const float* __restrict__ bhh,
    float* __restrict__ ht, __hip_bfloat16* __restrict__ hseq, int t,
    int h0, int b0, float ct_reg[2], float* smem, int tid)
{
    float (*As)[16][18]    = (float(*)[16][18])smem;
    float (*Bs)[16][4][33] = (float(*)[16][4][33])(smem + 2 * 16 * 18);
    const int hx = tid & 31;
    const int rp = tid >> 5;
    float acc[2][4] = {{0.f,0.f,0.f,0.f},{0.f,0.f,0.f,0.f}};

    const int NC1 = (D2 + 15) >> 4;   // 19
    const int NC2 = HH >> 4;          // 32
    const int NC = NC1 + NC2;         // 51

    float ra, rb[8];
    auto load_regs = [&](int c) {
        const float* Ap; const float* W; int lda, K, k0;
        if (c < NC1) { Ap = xt2; W = Wih; lda = D2; K = D2; k0 = c << 4; }
        else         { Ap = ht2; W = Whh; lda = HH; K = HH; k0 = (c - NC1) << 4; }
        int kk = tid & 15, r = tid >> 4;
        ra = (k0 + kk < K) ? ld_sc(&Ap[(b0 + r) * lda + k0 + kk]) : 0.f;
#pragma unroll
        for (int i = 0; i < 8; ++i) {
            int e2 = tid + (i << 8);
            int kk2 = e2 >> 7, cc = e2 & 127, s = cc >> 5, hh = cc & 31;
            rb[i] = (k0 + kk2 < K) ? W[(size_t)(k0 + kk2) * 2048 + s * 512 + h0 + hh] : 0.f;
        }
    };
    auto store_lds = [&](int buf) {
        As[buf][tid & 15][tid >> 4] = ra;
#pragma unroll
        for (int i = 0; i < 8; ++i) {
            int e2 = tid + (i << 8);
            int kk2 = e2 >> 7, cc = e2 & 127, s = cc >> 5, hh = cc & 31;
            Bs[buf][kk2][s][hh] = rb[i];
        }
    };

    load_regs(0); store_lds(0);
    for (int c = 0; c < NC; ++c) {
        __syncthreads();
        if (c + 1 < NC) load_regs(c + 1);
        const int buf = c & 1;
#pragma unroll
        for (int kk = 0; kk < 16; ++kk) {
            float2 a = *(const float2*)&As[buf][kk][rp * 2];
            float b0v = Bs[buf][kk][0][hx];
            float b1v = Bs[buf][kk][1][hx];
            float b2v = Bs[buf][kk][2][hx];
            float b3v = Bs[buf][kk][3][hx];
            acc[0][0] += a.x * b0v; acc[0][1] += a.x * b1v;
            acc[0][2] += a.x * b2v; acc[0][3] += a.x * b3v;
            acc[1][0] += a.y * b0v; acc[1][1] += a.y * b1v;
            acc[1][2] += a.y * b2v; acc[1][3] += a.y * b3v;
        }
        if (c + 1 < NC) store_lds((c + 1) & 1);
    }

    const int h = h0 + hx;
    const float bi0 = bih[h] + bhh[h];
    const float bi1 = bih[512 + h] + bhh[512 + h];
    const float bi2 = bih[1024 + h] + bhh[1024 + h];
    const float bi3 = bih[1536 + h] + bhh[1536 + h];
#pragma unroll
    for (int j = 0; j < 2; ++j) {
        const int r = b0 + rp * 2 + j;
        const float ig = acc[j][0] + bi0;
        const float fg = acc[j][1] + bi1;
        const float gg = acc[j][2] + bi2;
        const float og = acc[j][3] + bi3;
        const float cn = sigf(fg) * ct_reg[j] + sigf(ig) * tanhf(gg);
        const float hn = sigf(og) * tanhf(cn);
        ct_reg[j] = cn;
        st_sc(&ht[(size_t)r * 512 + h], hn);
        hseq[((size_t)r * SS + t) * 512 + h] = __float2bfloat16(hn);
    }
}

// ---------------------------------------------------------------------------
// Persistent scan: custom sc1 barriers, zero L2 invalidation.
// ---------------------------------------------------------------------------
__global__ __launch_bounds__(256, 1) void scan_kernel(
    const float* __restrict__ xp,
    const float* __restrict__ Q, const float* __restrict__ R,
    const float* __restrict__ Wih, const float* __restrict__ Whh,
    const float* __restrict__ bih, const float* __restrict__ bhh,
    float* __restrict__ xt2, float* __restrict__ ht, float* __restrict__ ht2,
    float* __restrict__ ct_unused, __hip_bfloat16* __restrict__ hseq,
    int* __restrict__ bars)
{
    cg::grid_group grid = cg::this_grid();
    __shared__ float smem[2 * 16 * 18 + 2 * 16 * 4 * 33];   // 19.2 KB
    const int w = blockIdx.x;
    const int tid = threadIdx.x;

    const int h0 = (w & 15) * 32;     // phase-C column slice (fixed per WG)
    const int b0 = (w >> 4) * 16;     // phase-C row slice

    // init: this WG's ht slice (sc1), barrier counters; ct lives in registers.
    {
        int i = tid * 2;
        int r = i >> 5, c = i & 31;
        st_sc(&ht[(size_t)(b0 + r) * 512 + h0 + c], 0.f);
        st_sc(&ht[(size_t)(b0 + r) * 512 + h0 + c + 1], 0.f);
        if (tid < 3) {
            __hip_atomic_store(&bars[w * 3 + tid], 0, __ATOMIC_RELAXED,
                               __HIP_MEMORY_SCOPE_AGENT);
        }
    }
    float ct_reg[2] = {0.f, 0.f};
    grid.sync();    // one heavyweight sync to publish init

    for (int t = 0; t < SS; ++t) {
        if (w < 80) {
            mog_tile<false>(ht, HH, HH, Q, D2, xt2, D2,
                            xp + (size_t)t * BB * D2, D2,
                            (w / 5) * 16, (w % 5) * 64, smem, tid);
        }
        gbar(&bars[t * 3 + 0], tid);

        if (w < 128) {
            mog_tile<true>(xt2, D2, D2, R, HH, ht2, HH, ht, HH,
                           (w >> 3) * 16, (w & 7) * 64, smem, tid);
        }
        gbar(&bars[t * 3 + 1], tid);

        gates_tile(xt2, ht2, Wih, Whh, bih, bhh, ht, hseq, t,
                   h0, b0, ct_reg, smem, tid);
        gbar(&bars[t * 3 + 2], tid);
    }
}

// ---------------------------------------------------------------------------
// Conv + relu + maxpool over time. One WG per batch row. hseq is bf16.
// ---------------------------------------------------------------------------
__global__ __launch_bounds__(256) void conv_kernel(
    const __hip_bfloat16* __restrict__ hseq,
    const float* __restrict__ w3, const float* __restrict__ cb3,
    const float* __restrict__ w4, const float* __restrict__ cb4,
    const float* __restrict__ w5, const float* __restrict__ cb5,
    float* __restrict__ feats)
{
    __shared__ float sh[20 * 516];
    __shared__ float part[16 * 16 * 9];
    __shared__ int rmax[9];
    const int b = blockIdx.x;
    const int tid = threadIdx.x;
    if (tid < 9) rmax[tid] = 0;
    const int wv = tid >> 6, lane = tid & 63;
    const int t0l = lane >> 2, hs = lane & 3;

    for (int p = 0; p < 16; ++p) {
        __syncthreads();
#pragma unroll
        for (int i = 0; i < 5; ++i) {
            int e = tid + (i << 8);
            int row = e >> 6, q = e & 63;
            int tg = p * 16 + row;
            float v[8];
            if (tg < SS) {
                uint4 u = *(const uint4*)(hseq + (((size_t)b * SS + tg) << 9) + (q << 3));
                v[0] = __uint_as_float(u.x << 16); v[1] = __uint_as_float(u.x & 0xffff0000u);
                v[2] = __uint_as_float(u.y << 16); v[3] = __uint_as_float(u.y & 0xffff0000u);
                v[4] = __uint_as_float(u.z << 16); v[5] = __uint_as_float(u.z & 0xffff0000u);
                v[6] = __uint_as_float(u.w << 16); v[7] = __uint_as_float(u.w & 0xffff0000u);
            } else {
#pragma unroll
                for (int j = 0; j < 8; ++j) v[j] = 0.f;
            }
#pragma unroll
            for (int j = 0; j < 8; ++j) sh[row * 516 + q * 8 + j] = v[j];
        }
        __syncthreads();

        float acc[9];
#pragma unroll
        for (int j = 0; j < 9; ++j) acc[j] = 0.f;
        for (int k = 0; k < 32; ++k) {
            const int h = (wv << 7) + (k << 2) + hs;
            const float v0 = sh[(t0l + 0) * 516 + h];
            const float v1 = sh[(t0l + 1) * 516 + h];
            const float v2 = sh[(t0l + 2) * 516 + h];
            const float v3 = sh[(t0l + 3) * 516 + h];
            const float v4 = sh[(t0l + 4) * 516 + h];
#pragma unroll
            for (int f = 0; f < 3; ++f) {
                acc[f]     += v0 * w3[(f * 3 + 0) * 512 + h] + v1 * w3[(f * 3 + 1) * 512 + h]
                            + v2 * w3[(f * 3 + 2) * 512 + h];
                acc[3 + f] += v0 * w4[(f * 4 + 0) * 512 + h] + v1 * w4[(f * 4 + 1) * 512 + h]
                            + v2 * w4[(f * 4 + 2) * 512 + h] + v3 * w4[(f * 4 + 3) * 512 + h];
                acc[6 + f] += v0 * w5[(f * 5 + 0) * 512 + h] + v1 * w5[(f * 5 + 1) * 512 + h]
                            + v2 * w5[(f * 5 + 2) * 512 + h] + v3 * w5[(f * 5 + 3) * 512 + h]
                            + v4 * w5[(f * 5 + 4) * 512 + h];
            }
        }
        const int pi = (wv << 2) + hs;
#pragma unroll
        for (int j = 0; j < 9; ++j) part[(pi * 16 + t0l) * 9 + j] = acc[j];
        __syncthreads();
        if (tid < 144) {
            const int tl = tid / 9, j = tid % 9;
            float s = 0.f;
#pragma unroll
            for (int pp = 0; pp < 16; ++pp) s += part[(pp * 16 + tl) * 9 + j];
            const int fsz = j < 3 ? 3 : (j < 6 ? 4 : 5);
            const int t0 = p * 16 + tl;
            if (t0 <= SS - fsz) {
                const float bias = j < 3 ? cb3[j] : (j < 6 ? cb4[j - 3] : cb5[j - 6]);
                float v = s + bias;
                v = v > 0.f ? v : 0.f;
                atomicMax(&rmax[j], __float_as_int(v));
            }
        }
    }
    __syncthreads();
    if (tid < 9) feats[b * 9 + tid] = __int_as_float(rmax[tid]);
}

__global__ void final_kernel(const float* __restrict__ feats,
                             const float* __restrict__ lin_w,
                             const float* __restrict__ lin_b,
                             float* __restrict__ out)
{
    const int b = threadIdx.x;
    float o0 = lin_b[0], o1 = lin_b[1];
#pragma unroll
    for (int j = 0; j < 9; ++j) {
        const float f = feats[b * 9 + j];
        o0 += f * lin_w[j * 2 + 0];
        o1 += f * lin_w[j * 2 + 1];
    }
    out[b * 2 + 0] = o0;
    out[b * 2 + 1] = o1;
}

extern "C" void kernel_launch(void* const* d_in, const int* in_sizes, int n_in,
                              void* d_out, int out_size, void* d_ws, size_t ws_size,
                              hipStream_t stream) {
    const float* x    = (const float*)d_in[0];
    const float* W_in = (const float*)d_in[1];
    const float* b_in = (const float*)d_in[2];
    const float* Wih  = (const float*)d_in[3];
    const float* Whh  = (const float*)d_in[4];
    const float* bih  = (const float*)d_in[5];
    const float* bhh  = (const float*)d_in[6];
    const float* Q    = (const float*)d_in[7];
    const float* R    = (const float*)d_in[8];
    const float* lin_w = (const float*)d_in[9];
    const float* lin_b = (const float*)d_in[10];
    const float* w3 = (const float*)d_in[11];
    const float* cb3 = (const float*)d_in[12];
    const float* w4 = (const float*)d_in[13];
    const float* cb4 = (const float*)d_in[14];
    const float* w5 = (const float*)d_in[15];
    const float* cb5 = (const float*)d_in[16];

    float* ws = (float*)d_ws;
    float* xp    = ws;                              // [S][B][300]
    float* xt2   = xp + (size_t)BB * SS * D2;
    float* ht    = xt2 + BB * D2;
    float* ht2   = ht + BB * HH;
    float* ct    = ht2 + BB * HH;                   // unused (registers now)
    float* feats = ct + BB * HH;
    __hip_bfloat16* hseq = (__hip_bfloat16*)(feats + BB * 9);
    int* bars = (int*)(hseq + (size_t)BB * SS * HH);   // 768 ints

    xp_kernel<<<dim3(5, 2048), 256, 0, stream>>>(x, W_in, b_in, xp);

    void* args[] = {(void*)&xp, (void*)&Q, (void*)&R, (void*)&Wih, (void*)&Whh,
                    (void*)&bih, (void*)&bhh, (void*)&xt2, (void*)&ht, (void*)&ht2,
                    (void*)&ct, (void*)&hseq, (void*)&bars};
    hipLaunchCooperativeKernel((const void*)scan_kernel, dim3(256), dim3(256),
                               args, 0, stream);

    conv_kernel<<<dim3(256), 256, 0, stream>>>(hseq, w3, cb3, w4, cb4, w5, cb5, feats);
    final_kernel<<<dim3(1), 256, 0, stream>>>(feats, lin_w, lin_b, (float*)d_out);
}